// Round 14
// baseline (134.715 us; speedup 1.0000x reference)
//
#include <hip/hip_runtime.h>
#include <hip/hip_bf16.h>

typedef __attribute__((ext_vector_type(8))) short bf16x8;
typedef __attribute__((ext_vector_type(4))) float f32x4;
typedef __attribute__((ext_vector_type(16))) float f32x16;

#define NHID 256
#define NDIM 128
#define NB   512

// hardware packed f32->bf16 RNE (gfx950 v_cvt_pk_bf16_f32; no builtin exposed).
__device__ __forceinline__ unsigned pk2bf(float a, float b) {
  unsigned r;
  asm("v_cvt_pk_bf16_f32 %0, %1, %2" : "=v"(r) : "v"(a), "v"(b));
  return r;
}

// ---------------- setup ----------------
// hx = x@Wx^T + b0, hy = y@Wy^T  (8 rows per block: W0 row loaded once, reused 8x)
// W1/W2 -> bf16 fragment-major for 32x32x16 MFMA:
//   frag f = kt*8 + gtile  (kt = k>>4, gtile = g>>5), 1 KB each.
//   lane l = (g&31) + 32*((k>>3)&1) holds W[g][kt*16 + (l>>5)*8 .. +8] as 8 bf16 at l*16 bytes.
__global__ void k_setup(const float* __restrict__ x, const float* __restrict__ y,
                        const float* __restrict__ W0, const float* __restrict__ b0,
                        const float* __restrict__ W1, const float* __restrict__ W2,
                        float* __restrict__ hx, float* __restrict__ hy,
                        unsigned short* __restrict__ W1f, unsigned short* __restrict__ W2f) {
  int bid = blockIdx.x, tid = threadIdx.x;
  if (bid < 128) {
    int which = bid & 1;                 // 0: hx (+b0), 1: hy
    int rowbase = (bid >> 1) * 8;
    const float* in = which ? y : x;
    const f32x4* wr = (const f32x4*)(W0 + tid * (2 * NDIM) + which * NDIM);
    f32x4 sv[8];
#pragma unroll
    for (int r = 0; r < 8; ++r) sv[r] = f32x4{0.f, 0.f, 0.f, 0.f};
#pragma unroll 4
    for (int i = 0; i < NDIM / 4; ++i) {
      f32x4 b = wr[i];
#pragma unroll
      for (int r = 0; r < 8; ++r) {
        f32x4 a = *(const f32x4*)(in + (rowbase + r) * NDIM + i * 4);
        sv[r] += a * b;
      }
    }
    float bb = which ? 0.f : b0[tid];
    float* o = (which ? hy : hx) + rowbase * NHID + tid;
#pragma unroll
    for (int r = 0; r < 8; ++r)
      o[r * NHID] = sv[r][0] + sv[r][1] + sv[r][2] + sv[r][3] + bb;
  } else {
    int i = ((bid - 128) * 256 + tid) * 4;        // 2*65536 elements total
    const float* src = W1; unsigned short* dst = W1f; int j = i;
    if (i >= NHID * NHID) { src = W2; dst = W2f; j = i - NHID * NHID; }
    float4 v = *(const float4*)(src + j);
    int g = j >> 8, k0 = j & 255;                 // 4 consecutive k, same g
    int f = ((k0 >> 4) << 3) + (g >> 5);
    int l = (g & 31) + (((k0 >> 3) & 1) << 5);
    uint2 pk; pk.x = pk2bf(v.x, v.y); pk.y = pk2bf(v.z, v.w);
    *(uint2*)(dst + f * 512 + l * 8 + (k0 & 7)) = pk;
  }
}

// ---------------- one layer (compute wave): tile 64g x 128m, 32x32x16 MFMA ----------------
// LDS h fragment-major: frag(kt, mt) at (kt*4 + mt)*1024 bytes, lane's 16B at lane*16 holds
//   h[m = mt*32 + (lane&31)][k = kt*16 + (lane>>5)*8 .. +8].
// Compute wave cw: g in [cw*64, +64) (gtiles 2cw, 2cw+1), m in [0,128).
// A rotates through Aa[2]/Ab[2], prefetch distance 2; at kt=14/15 the SAME slots are
// reloaded with the NEXT layer/task's kt0/kt1 fragments (fbn) — zero extra registers.
__device__ __forceinline__ void layer16(const unsigned short* __restrict__ fb,
                                        const unsigned short* __restrict__ fbn,
                                        const char* __restrict__ src_lane, // cbuf + lane*16
                                        f32x16 acc[2][4],
                                        bf16x8 Aa[2], bf16x8 Ab[2]) {
#pragma unroll
  for (int i = 0; i < 2; ++i)
#pragma unroll
    for (int j = 0; j < 4; ++j)
#pragma unroll
      for (int e = 0; e < 16; ++e) acc[i][j][e] = 0.f;

#pragma unroll
  for (int kt = 0; kt < 16; ++kt) {
    bf16x8 B0 = *(const bf16x8*)(src_lane + kt * 4096);
    bf16x8 B1 = *(const bf16x8*)(src_lane + kt * 4096 + 1024);
    bf16x8 B2 = *(const bf16x8*)(src_lane + kt * 4096 + 2048);
    bf16x8 B3 = *(const bf16x8*)(src_lane + kt * 4096 + 3072);
    bf16x8 A0 = Aa[kt & 1], A1 = Ab[kt & 1];
    __builtin_amdgcn_s_setprio(1);
    acc[0][0] = __builtin_amdgcn_mfma_f32_32x32x16_bf16(A0, B0, acc[0][0], 0, 0, 0);
    acc[1][0] = __builtin_amdgcn_mfma_f32_32x32x16_bf16(A1, B0, acc[1][0], 0, 0, 0);
    acc[0][1] = __builtin_amdgcn_mfma_f32_32x32x16_bf16(A0, B1, acc[0][1], 0, 0, 0);
    acc[1][1] = __builtin_amdgcn_mfma_f32_32x32x16_bf16(A1, B1, acc[1][1], 0, 0, 0);
    acc[0][2] = __builtin_amdgcn_mfma_f32_32x32x16_bf16(A0, B2, acc[0][2], 0, 0, 0);
    acc[1][2] = __builtin_amdgcn_mfma_f32_32x32x16_bf16(A1, B2, acc[1][2], 0, 0, 0);
    acc[0][3] = __builtin_amdgcn_mfma_f32_32x32x16_bf16(A0, B3, acc[0][3], 0, 0, 0);
    acc[1][3] = __builtin_amdgcn_mfma_f32_32x32x16_bf16(A1, B3, acc[1][3], 0, 0, 0);
    __builtin_amdgcn_s_setprio(0);
    if (kt + 2 < 16) {
      Aa[kt & 1] = *(const bf16x8*)(fb + (kt + 2) * 4096);
      Ab[kt & 1] = *(const bf16x8*)(fb + (kt + 2) * 4096 + 512);
    } else {
      Aa[kt & 1] = *(const bf16x8*)(fbn + (kt - 14) * 4096);
      Ab[kt & 1] = *(const bf16x8*)(fbn + (kt - 14) * 4096 + 512);
    }
  }
}

// builder: write 16B of frag(kt=jj, mt=cw) for jj in [j0, j1)
// (j0/j1 are literal at every call site -> fully unrolled after inlining)
__device__ __forceinline__ void build_chunk(const float* __restrict__ pxr,
                                            const float* __restrict__ pyr,
                                            char* __restrict__ wb, int j0, int j1) {
  const f32x4 vzero = {0.f, 0.f, 0.f, 0.f};
#pragma unroll
  for (int jj = j0; jj < j1; ++jj) {
    int ko = jj * 16;
    f32x4 x0 = *(const f32x4*)(pxr + ko);
    f32x4 x1 = *(const f32x4*)(pxr + ko + 4);
    f32x4 y0 = *(const f32x4*)(pyr + ko);
    f32x4 y1 = *(const f32x4*)(pyr + ko + 4);
    f32x4 a = __builtin_elementwise_max(x0 + y0, vzero);
    f32x4 b = __builtin_elementwise_max(x1 + y1, vzero);
    uint4 pk;
    pk.x = pk2bf(a[0], a[1]);
    pk.y = pk2bf(a[2], a[3]);
    pk.z = pk2bf(b[0], b[1]);
    pk.w = pk2bf(b[2], b[3]);
    *(uint4*)(wb + jj * 4096) = pk;
  }
}

// ---------------- main fused kernel: producer/consumer wave specialization ----------------
// 256 blocks (1/CU) x 512 threads (8 waves). Waves 0-3 COMPUTE (L1/epi/L2/head on cbuf,
// 64g x 128m each, acc = 128 AGPR). Waves 4-7 BUILD task t+1's h0 into bbuf concurrently.
// Every barrier interval contains MFMA (compute waves) AND VALU/global (builder waves):
// the pipes overlap at CU level regardless of per-wave serialization (m114 mechanism).
// One compute + one builder wave per SIMD (wv&3 pairing). 8 tasks of 128 pairs per block.
__global__ __launch_bounds__(512, 2) void k_main(
    const float* __restrict__ hx, const float* __restrict__ hy,
    const unsigned short* __restrict__ W1f, const unsigned short* __restrict__ W2f,
    const float* __restrict__ bias1, const float* __restrict__ bias2,
    const float* __restrict__ w3, const float* __restrict__ b3,
    float* __restrict__ out) {
  extern __shared__ __align__(16) char dbuf[];   // 2 x 64 KB h-buffers + 2 KB stg
  float* stg = (float*)(dbuf + 131072);          // [4 compute waves][128 m]

  const int tid = threadIdx.x;
  const int bid = blockIdx.x;
  const int a0i   = (bid >> 2) * 8;    // 64 a-groups of 8 rows
  const int bbase = (bid & 3) * 128;   // 4 b-supergroups of 128 cols

  const int lane = tid & 63, wv = tid >> 6;   // 8 waves
  const int c = lane & 31, l5 = lane >> 5;
  const int cw = wv & 3;                      // role-local wave index
  const bool is_comp = (wv < 4);
  const f32x4 vzero = {0.f, 0.f, 0.f, 0.f};

  // ---- compute-wave state ----
  const unsigned short* fbW1 = W1f + cw * 1024 + lane * 8;   // + kt*4096, +512 2nd gtile
  const unsigned short* fbW2 = W2f + cw * 1024 + lane * 8;
  bf16x8 Aa[2], Ab[2];
  if (is_comp) {          // prime A rotation with W1 kt0/kt1 (hides under prologue build)
    Aa[0] = *(const bf16x8*)(fbW1);
    Ab[0] = *(const bf16x8*)(fbW1 + 512);
    Aa[1] = *(const bf16x8*)(fbW1 + 4096);
    Ab[1] = *(const bf16x8*)(fbW1 + 4096 + 512);
  }

  // ---- builder-wave state: thread owns 16B of frag(*, mt=cw), m = cw*32 + c ----
  const int m = cw * 32 + c;
  const float* pxr = hx + (a0i + (m >> 4)) * NHID + l5 * 8;   // a-row fixed across tasks
  const float* pyb = hy + (m & 15) * NHID + l5 * 8;           // + bb0*NHID per task
  const int wboff = cw * 1024 + lane * 16;

  char* cbuf = dbuf;             // computers' h-buffer (h0 -> h1 in place)
  char* bbuf = dbuf + 65536;     // builders' target (next task's h0)

  // ---- prologue: builders build task0's full h0 into cbuf ----
  if (!is_comp) build_chunk(pxr, pyb + bbase * NHID, cbuf + wboff, 0, 16);
  __syncthreads();

#pragma unroll 1
  for (int t = 0; t < 8; ++t) {
    const int bb0 = bbase + t * 16;
    f32x16 acc[2][4];

    // ---- phase 1: L1 (compute)  ||  build[t+1] first half (builders) ----
    if (is_comp) {
      layer16(fbW1, fbW2, cbuf + lane * 16, acc, Aa, Ab);
    } else if (t + 1 < 8) {
      build_chunk(pxr, pyb + (bb0 + 16) * NHID, bbuf + wboff, 0, 8);
    }
    __syncthreads();   // L1 reads of cbuf done -> epi may overwrite

    // ---- phase 2: epilogue h1 -> cbuf (compute)  ||  build[t+1] second half ----
    if (is_comp) {
      // acc[gt][mt][r]: m = mt*32+c, g = cw*64 + gt*32 + rg*8 + l5*4 + (r&3)  (rg=r>>2).
      // Dest frag f' = (g>>4)*4 + (m>>5) = ((cw*4 + gt*2 + (rg>>1)))*4 + mt,
      //   lane slot l' = c + 32*(rg&1), byte l'*16 + l5*8 (8B store of 4 bf16).
#pragma unroll
      for (int gt = 0; gt < 2; ++gt) {
#pragma unroll
        for (int rg = 0; rg < 4; ++rg) {
          f32x4 bv = *(const f32x4*)(bias1 + cw * 64 + gt * 32 + rg * 8 + l5 * 4);
          char* wa = cbuf + (c + ((rg & 1) << 5)) * 16 + l5 * 8;
          int fbase = (cw * 4 + gt * 2 + (rg >> 1)) * 4;
#pragma unroll
          for (int mt = 0; mt < 4; ++mt) {
            f32x16 v = acc[gt][mt];
            f32x4 tt = {v[rg * 4 + 0], v[rg * 4 + 1], v[rg * 4 + 2], v[rg * 4 + 3]};
            tt = __builtin_elementwise_max(tt + bv, vzero);
            uint2 pk;
            pk.x = pk2bf(tt[0], tt[1]);
            pk.y = pk2bf(tt[2], tt[3]);
            *(uint2*)(wa + (fbase + mt) * 1024) = pk;
          }
        }
      }
    } else if (t + 1 < 8) {
      build_chunk(pxr, pyb + (bb0 + 16) * NHID, bbuf + wboff, 8, 16);
    }
    __syncthreads();   // h1 complete in cbuf; h0[t+1] complete in bbuf

    // ---- phase 3: L2 + head partials (compute only) ----
    if (is_comp) {
      layer16(fbW2, fbW1, cbuf + lane * 16, acc, Aa, Ab);   // tail reloads W1 for next task
      float s[4];
      {
        f32x4 sv[4];
#pragma unroll
        for (int mt = 0; mt < 4; ++mt) sv[mt] = vzero;
#pragma unroll
        for (int gt = 0; gt < 2; ++gt) {
#pragma unroll
          for (int rg = 0; rg < 4; ++rg) {
            int g0 = cw * 64 + gt * 32 + rg * 8 + l5 * 4;
            f32x4 bv  = *(const f32x4*)(bias2 + g0);
            f32x4 wvv = *(const f32x4*)(w3 + g0);
#pragma unroll
            for (int mt = 0; mt < 4; ++mt) {
              f32x16 v = acc[gt][mt];
              f32x4 tt = {v[rg * 4 + 0], v[rg * 4 + 1], v[rg * 4 + 2], v[rg * 4 + 3]};
              tt = __builtin_elementwise_max(tt + bv, vzero);
              sv[mt] += tt * wvv;
            }
          }
        }
#pragma unroll
        for (int mt = 0; mt < 4; ++mt) {
          float tt = sv[mt][0] + sv[mt][1] + sv[mt][2] + sv[mt][3];
          tt += __shfl_xor(tt, 32);        // combine the two l5 halves (different g-quads)
          s[mt] = tt;
        }
      }
      if (l5 == 0) {
#pragma unroll
        for (int mt = 0; mt < 4; ++mt) stg[cw * 128 + mt * 32 + c] = s[mt];
      }
    }
    __syncthreads();   // stg ready; all L2 reads of cbuf done

    // ---- phase 4: output write; swap buffers ----
    if (tid < 128) {
      float v = b3[0];
#pragma unroll
      for (int w = 0; w < 4; ++w) v += stg[w * 128 + tid];
      out[(a0i + (tid >> 4)) * NB + bb0 + (tid & 15)] = v;
    }
    { char* tmp = cbuf; cbuf = bbuf; bbuf = tmp; }
    __syncthreads();   // out-write done (stg reusable); builders may overwrite old cbuf
  }
}

extern "C" void kernel_launch(void* const* d_in, const int* in_sizes, int n_in,
                              void* d_out, int out_size, void* d_ws, size_t ws_size,
                              hipStream_t stream) {
  const float* x  = (const float*)d_in[0];
  const float* y  = (const float*)d_in[1];
  const float* W0 = (const float*)d_in[2];
  const float* b0 = (const float*)d_in[3];
  const float* W1 = (const float*)d_in[4];
  const float* b1 = (const float*)d_in[5];
  const float* W2 = (const float*)d_in[6];
  const float* b2 = (const float*)d_in[7];
  const float* W3 = (const float*)d_in[8];
  const float* b3 = (const float*)d_in[9];
  float* out = (float*)d_out;

  char* ws = (char*)d_ws;
  float* hx = (float*)ws;                               // 512*256*4 = 512 KB
  float* hy = (float*)(ws + 524288);                    // 512 KB
  unsigned short* W1f = (unsigned short*)(ws + 1048576);          // 128 KB
  unsigned short* W2f = (unsigned short*)(ws + 1048576 + 131072); // 128 KB

  static bool attr_set = false;
  if (!attr_set) {
    hipFuncSetAttribute(reinterpret_cast<const void*>(k_main),
                        hipFuncAttributeMaxDynamicSharedMemorySize, 133120);
    attr_set = true;
  }

  k_setup<<<dim3(256), dim3(256), 0, stream>>>(x, y, W0, b0, W1, W2, hx, hy, W1f, W2f);
  k_main<<<dim3(256), dim3(512), 133120, stream>>>(hx, hy, W1f, W2f, b1, b2, W3, b3, out);
}